// Round 15
// baseline (234.605 us; speedup 1.0000x reference)
//
#include <hip/hip_runtime.h>
#include <math.h>

// Problem constants (B=1): S=4096, D=128, NHEADS=4, hd=32, N_COE=50, N_SCALES=4, THRE=5
//
// ws layout (floats):
//   eig   @ 0        (524288)
//   qkv   @ 524288   (1572864; only Q panel used, f32)
//   Oe    @ 2097152  (4*4096*128)
//   E     @ 4194304  (4*4*4096)
//   xsum  @ 4259840  (128)
//   coef  @ 4259968  (104; pad)
//   Khi_g @ 4260352  [h][key][d] bf16 hi
//   Klo_g @ 4522496  [h][key][d] bf16 lo
//   Vt_g  @ 4784640  [h*32+d][key] bf16
// total ~20 MB

#define KSPLIT 4

typedef __attribute__((ext_vector_type(8))) short short8;   // 8 bf16
typedef __attribute__((ext_vector_type(4))) short short4v;  // 4 bf16 (8B)
typedef __attribute__((ext_vector_type(4))) float f32x4;

__device__ inline unsigned short f2bf(float x) {            // RNE f32->bf16 bits
    unsigned u = __float_as_uint(x);
    return (unsigned short)((u + 0x7FFFu + ((u >> 16) & 1u)) >> 16);
}
__device__ inline float bf2f(unsigned short h) { return __uint_as_float(((unsigned)h) << 16); }

// ---------------- K1: fused sine-encoding + eig GEMM + LN1 + qkv GEMM (unchanged) ----------------
__global__ __launch_bounds__(256) void k_embed(const float* __restrict__ eve,
    const float* __restrict__ eigW, const float* __restrict__ ebias,
    const float* __restrict__ g, const float* __restrict__ b,
    const float* __restrict__ inW, const float* __restrict__ inb,
    float* __restrict__ eig, float* __restrict__ qkv, unsigned short* __restrict__ Khi_g,
    unsigned short* __restrict__ Klo_g, unsigned short* __restrict__ Vt_g)
{
    __shared__ __align__(16) float wsh[129 * 128];   // staged weight panel (66 KB)
    __shared__ __align__(16) float se[16][132];      // [0..63]=sin, [64..127]=cos, [128]=e
    __shared__ __align__(16) float xn[16][132];      // LN1 output
    __shared__ __align__(16) unsigned short vsh[128][16];
    const int t = threadIdx.x;
    const int r0 = blockIdx.x * 16;
    {   // Phase A: sin/cos (16 rows x 16 threads/row x 4 j)
        const int r = t >> 4, l4 = t & 15;
        const float e = eve[r0 + r];
        if (l4 == 0) se[r][128] = e;
        #pragma unroll
        for (int jj = 0; jj < 4; ++jj) {
            const int j = l4 * 4 + jj;
            const float div = __expf(-0.07195578415606394f * (float)(2 * j));
            const float pe = e * 100.0f * div;    // |pe| <= 200 rad
            se[r][j]      = __sinf(pe);
            se[r][64 + j] = __cosf(pe);
        }
    }
    {   // stage eigW (129 rows x 128) -> wsh
        const float4* __restrict__ src = (const float4*)eigW;
        float4* dst = (float4*)wsh;
        #pragma unroll
        for (int i = 0; i < 17; ++i) {
            const int f = t + i * 256;
            if (f < 4128) dst[f] = src[f];
        }
    }
    __syncthreads();
    const int lane = t & 63;
    const int w = t >> 6;
    const int rp = w * 2 + (lane >> 5);           // 0..7
    const int c0 = (lane & 31) * 4;
    const int ra = rp * 2, rb = ra + 1;
    float xa[4], xb[4];                            // eig rows ra/rb, cols c0..c0+3
    {   // Phase B: eig = eeig @ W + b (weights from LDS)
        const float4 w0 = *(const float4*)&wsh[c0];
        const float ea = se[ra][128], eb = se[rb][128];
        float a0 = ea * w0.x, a1 = ea * w0.y, a2 = ea * w0.z, a3 = ea * w0.w;
        float b0 = eb * w0.x, b1 = eb * w0.y, b2 = eb * w0.z, b3 = eb * w0.w;
        #pragma unroll 8
        for (int k = 0; k < 128; ++k) {           // se[.][k] pairs wsh row k+1
            const float xva = se[ra][k];
            const float xvb = se[rb][k];
            const float4 wk = *(const float4*)&wsh[(k + 1) * 128 + c0];
            a0 = fmaf(xva, wk.x, a0); a1 = fmaf(xva, wk.y, a1);
            a2 = fmaf(xva, wk.z, a2); a3 = fmaf(xva, wk.w, a3);
            b0 = fmaf(xvb, wk.x, b0); b1 = fmaf(xvb, wk.y, b1);
            b2 = fmaf(xvb, wk.z, b2); b3 = fmaf(xvb, wk.w, b3);
        }
        const float4 bb = *(const float4*)&ebias[c0];
        xa[0] = a0 + bb.x; xa[1] = a1 + bb.y; xa[2] = a2 + bb.z; xa[3] = a3 + bb.w;
        xb[0] = b0 + bb.x; xb[1] = b1 + bb.y; xb[2] = b2 + bb.z; xb[3] = b3 + bb.w;
        *(float4*)&eig[(size_t)(r0 + ra) * 128 + c0] = make_float4(xa[0], xa[1], xa[2], xa[3]);
        *(float4*)&eig[(size_t)(r0 + rb) * 128 + c0] = make_float4(xb[0], xb[1], xb[2], xb[3]);
    }
    {   // Phase C: LN1 for both rows — half-wave shuffle
        float sa = (xa[0] + xa[1]) + (xa[2] + xa[3]);
        float qa = (xa[0] * xa[0] + xa[1] * xa[1]) + (xa[2] * xa[2] + xa[3] * xa[3]);
        float sb = (xb[0] + xb[1]) + (xb[2] + xb[3]);
        float qb = (xb[0] * xb[0] + xb[1] * xb[1]) + (xb[2] * xb[2] + xb[3] * xb[3]);
        #pragma unroll
        for (int m = 1; m < 32; m <<= 1) {
            sa += __shfl_xor(sa, m, 32); qa += __shfl_xor(qa, m, 32);
            sb += __shfl_xor(sb, m, 32); qb += __shfl_xor(qb, m, 32);
        }
        const float ma = sa * (1.f / 128.f), mb = sb * (1.f / 128.f);
        const float ia = 1.f / sqrtf(qa * (1.f / 128.f) - ma * ma + 1e-5f);
        const float ib = 1.f / sqrtf(qb * (1.f / 128.f) - mb * mb + 1e-5f);
        const float4 gg = *(const float4*)&g[c0];
        const float4 bb = *(const float4*)&b[c0];
        *(float4*)&xn[ra][c0] = make_float4((xa[0] - ma) * ia * gg.x + bb.x,
                                            (xa[1] - ma) * ia * gg.y + bb.y,
                                            (xa[2] - ma) * ia * gg.z + bb.z,
                                            (xa[3] - ma) * ia * gg.w + bb.w);
        *(float4*)&xn[rb][c0] = make_float4((xb[0] - mb) * ib * gg.x + bb.x,
                                            (xb[1] - mb) * ib * gg.y + bb.y,
                                            (xb[2] - mb) * ib * gg.z + bb.z,
                                            (xb[3] - mb) * ib * gg.w + bb.w);
    }
    // Phase D: qkv GEMM, one panel at a time (stage -> gemm -> writeback)
    const int rowa = r0 + ra, rowb = r0 + rb;
    for (int p = 0; p < 3; ++p) {
        __syncthreads();                           // prev wsh reads done; xn ready (p==0)
        {   // stage inW panel p: wsh[k*128+c] = inW[k*384 + p*128 + c]
            const float4* __restrict__ src = (const float4*)inW;   // row = 96 float4
            float4* dst = (float4*)wsh;
            #pragma unroll
            for (int i = 0; i < 16; ++i) {
                const int f = t + i * 256;         // 0..4095
                const int k = f >> 5, c4 = f & 31;
                dst[f] = src[k * 96 + p * 32 + c4];
            }
        }
        __syncthreads();
        float A[4], B[4];
        {
            const float4 bb = *(const float4*)&inb[p * 128 + c0];
            A[0] = bb.x; A[1] = bb.y; A[2] = bb.z; A[3] = bb.w;
            B[0] = bb.x; B[1] = bb.y; B[2] = bb.z; B[3] = bb.w;
        }
        #pragma unroll 8
        for (int k = 0; k < 128; ++k) {
            const float xva = xn[ra][k];
            const float xvb = xn[rb][k];
            const float4 wk = *(const float4*)&wsh[k * 128 + c0];
            A[0] = fmaf(xva, wk.x, A[0]); A[1] = fmaf(xva, wk.y, A[1]);
            A[2] = fmaf(xva, wk.z, A[2]); A[3] = fmaf(xva, wk.w, A[3]);
            B[0] = fmaf(xvb, wk.x, B[0]); B[1] = fmaf(xvb, wk.y, B[1]);
            B[2] = fmaf(xvb, wk.z, B[2]); B[3] = fmaf(xvb, wk.w, B[3]);
        }
        if (p == 0) {          // Q: f32
            *(float4*)&qkv[(size_t)rowa * 384 + c0] = make_float4(A[0], A[1], A[2], A[3]);
            *(float4*)&qkv[(size_t)rowb * 384 + c0] = make_float4(B[0], B[1], B[2], B[3]);
        } else if (p == 1) {   // K: bf16 hi/lo, [h][key][d]
            const int h = c0 >> 5, d = c0 & 31;
            unsigned short h4[4], l4v[4];
            #pragma unroll
            for (int i = 0; i < 4; ++i) { h4[i] = f2bf(A[i]); l4v[i] = f2bf(A[i] - bf2f(h4[i])); }
            *(uint2*)&Khi_g[((size_t)h * 4096 + rowa) * 32 + d] = *(uint2*)h4;
            *(uint2*)&Klo_g[((size_t)h * 4096 + rowa) * 32 + d] = *(uint2*)l4v;
            #pragma unroll
            for (int i = 0; i < 4; ++i) { h4[i] = f2bf(B[i]); l4v[i] = f2bf(B[i] - bf2f(h4[i])); }
            *(uint2*)&Khi_g[((size_t)h * 4096 + rowb) * 32 + d] = *(uint2*)h4;
            *(uint2*)&Klo_g[((size_t)h * 4096 + rowb) * 32 + d] = *(uint2*)l4v;
        } else {               // V: bf16 via LDS transpose
            #pragma unroll
            for (int i = 0; i < 4; ++i) {
                vsh[c0 + i][ra] = f2bf(A[i]);
                vsh[c0 + i][rb] = f2bf(B[i]);
            }
        }
    }
    __syncthreads();
    if (t < 128) {   // V transpose flush: 16 keys of column t
        const uint4 v0 = *(const uint4*)&vsh[t][0];
        const uint4 v1 = *(const uint4*)&vsh[t][8];
        *(uint4*)&Vt_g[(size_t)t * 4096 + r0]     = v0;
        *(uint4*)&Vt_g[(size_t)t * 4096 + r0 + 8] = v1;
    }
}

// ---------------- K3: MFMA flash attention, 1 wave/block, 4 Q-frags/wave ----------------
// Wave owns 64 queries (4 Q-fragments in regs) x 1024-key slot. K/V/P LDS is wave-private:
// NO barriers (same-wave DS ordering + compiler waitcnts). Each K-fragment read feeds 12
// MFMAs (4 Qfrags x 3 split-bf16 terms) vs 3 before — 4x LDS amortization.
#define KSTR 40
#define VSTR 72
#define PSTR 72

__global__ __launch_bounds__(64) void k_attn(const float* __restrict__ qkv,
    const unsigned short* __restrict__ Khi_g, const unsigned short* __restrict__ Klo_g,
    const unsigned short* __restrict__ Vt_g,
    const int* __restrict__ sele, float* __restrict__ Oe, float* __restrict__ E)
{
    __shared__ __align__(16) unsigned short Khi[64 * KSTR];
    __shared__ __align__(16) unsigned short Klo[64 * KSTR];
    __shared__ __align__(16) unsigned short Vt[32 * VSTR];
    __shared__ __align__(16) unsigned short Pw[64 * PSTR];

    const int lane = threadIdx.x;
    const int l = lane & 15;
    const int quad = lane >> 4;
    const int qb = blockIdx.x;   // 64 q-blocks of 64 queries
    const int h  = blockIdx.y;   // 4 heads
    const int ks = blockIdx.z;   // 4 key slots of 1024
    const int nk = sele[0];

    short8 qhi[4], qlo[4];       // 4 Q-fragments: queries qb*64 + qf*16 + l
    #pragma unroll
    for (int qf = 0; qf < 4; ++qf) {
        const float* __restrict__ qr =
            qkv + (size_t)(qb * 64 + qf * 16 + l) * 384 + h * 32 + quad * 8;
        const float4 a = *(const float4*)qr;
        const float4 b = *(const float4*)(qr + 4);
        const float sc = 0.17677669529663687f;   // 1/sqrt(32)
        float v[8] = {a.x * sc, a.y * sc, a.z * sc, a.w * sc, b.x * sc, b.y * sc, b.z * sc, b.w * sc};
        #pragma unroll
        for (int j = 0; j < 8; ++j) {
            const unsigned short hb = f2bf(v[j]);
            qhi[qf][j] = (short)hb;
            qlo[qf][j] = (short)f2bf(v[j] - bf2f(hb));
        }
    }
    f32x4 accO[4][2];
    #pragma unroll
    for (int qf = 0; qf < 4; ++qf) {
        accO[qf][0] = (f32x4){0.f, 0.f, 0.f, 0.f};
        accO[qf][1] = (f32x4){0.f, 0.f, 0.f, 0.f};
    }
    float elane[4] = {0.f, 0.f, 0.f, 0.f};

    for (int ch = 0; ch < 16; ++ch) {
        const int keybase = ks * 1024 + ch * 64;
        {   // stage K hi/lo + V for this chunk (wave-private; conflict-free maps)
            uint4 kh[4], kl4[4], vv[4];
            #pragma unroll
            for (int j = 0; j < 4; ++j) {
                const int kk = (lane >> 2) + 16 * j;
                const int o4 = (lane & 3) * 8;
                kh[j]  = *(const uint4*)&Khi_g[((size_t)h * 4096 + keybase + kk) * 32 + o4];
                kl4[j] = *(const uint4*)&Klo_g[((size_t)h * 4096 + keybase + kk) * 32 + o4];
            }
            #pragma unroll
            for (int j = 0; j < 4; ++j) {
                const int vd = (lane >> 3) + 8 * j;
                const int ko = (lane & 7) * 8;
                vv[j] = *(const uint4*)&Vt_g[((size_t)h * 32 + vd) * 4096 + keybase + ko];
            }
            #pragma unroll
            for (int j = 0; j < 4; ++j) {
                const int kk = (lane >> 2) + 16 * j;
                const int o4 = (lane & 3) * 8;
                *(uint4*)&Khi[kk * KSTR + o4] = kh[j];
                *(uint4*)&Klo[kk * KSTR + o4] = kl4[j];
            }
            #pragma unroll
            for (int j = 0; j < 4; ++j) {
                const int vd = (lane >> 3) + 8 * j;
                const int ko = (lane & 7) * 8;
                *(uint4*)&Vt[vd * VSTR + ko] = vv[j];
            }
        }
        // QK^T transposed (A=K, B=Q): each K-fragment feeds all 4 Q-frags
        #pragma unroll
        for (int tile = 0; tile < 4; ++tile) {
            const int kl = tile * 16 + l;
            const short8 kh = *(const short8*)&Khi[kl * KSTR + quad * 8];
            const short8 kw = *(const short8*)&Klo[kl * KSTR + quad * 8];
            const int kg0 = keybase + tile * 16 + quad * 4;
            #pragma unroll
            for (int qf = 0; qf < 4; ++qf) {
                f32x4 S = {0.f, 0.f, 0.f, 0.f};
                S = __builtin_amdgcn_mfma_f32_16x16x32_bf16(kh, qhi[qf], S, 0, 0, 0);
                S = __builtin_amdgcn_mfma_f32_16x16x32_bf16(kw, qhi[qf], S, 0, 0, 0);
                S = __builtin_amdgcn_mfma_f32_16x16x32_bf16(kh, qlo[qf], S, 0, 0, 0);
                short4v pw;
                #pragma unroll
                for (int r = 0; r < 4; ++r) {
                    const float p = (kg0 + r < nk) ? __expf(S[r]) : 0.f;
                    elane[qf] += p;
                    pw[r] = (short)f2bf(p);
                }
                *(short4v*)&Pw[(qf * 16 + l) * PSTR + tile * 16 + quad * 4] = pw;
            }
        }
        // PV: V-fragments shared across the 4 Q-frags
        #pragma unroll
        for (int step = 0; step < 2; ++step) {
            const short8 vb0 = *(const short8*)&Vt[l * VSTR + step * 32 + quad * 8];
            const short8 vb1 = *(const short8*)&Vt[(16 + l) * VSTR + step * 32 + quad * 8];
            #pragma unroll
            for (int qf = 0; qf < 4; ++qf) {
                const short8 pa = *(const short8*)&Pw[(qf * 16 + l) * PSTR + step * 32 + quad * 8];
                accO[qf][0] = __builtin_amdgcn_mfma_f32_16x16x32_bf16(pa, vb0, accO[qf][0], 0, 0, 0);
                accO[qf][1] = __builtin_amdgcn_mfma_f32_16x16x32_bf16(pa, vb1, accO[qf][1], 0, 0, 0);
            }
        }
    }
    #pragma unroll
    for (int qf = 0; qf < 4; ++qf) {
        float e = elane[qf];
        e += __shfl_xor(e, 16, 64);
        e += __shfl_xor(e, 32, 64);
        if (lane < 16)
            E[((size_t)ks * 4 + h) * 4096 + qb * 64 + qf * 16 + l] = e;
        #pragma unroll
        for (int r = 0; r < 4; ++r) {
            const size_t row = qb * 64 + qf * 16 + quad * 4 + r;
            Oe[((size_t)ks * 4096 + row) * 128 + h * 32 + l]      = accO[qf][0][r];
            Oe[((size_t)ks * 4096 + row) * 128 + h * 32 + 16 + l] = accO[qf][1][r];
        }
    }
}

// ---------------- K4: fold + out-proj + residual + LN2 + FFN + column-sum (unchanged) ----------------
__global__ __launch_bounds__(256) void k_ffn(const float* __restrict__ eig,
    const float* __restrict__ Oe, const float* __restrict__ E,
    const float* __restrict__ outW, const float* __restrict__ outb,
    const float* __restrict__ lg, const float* __restrict__ lb,
    const float* __restrict__ W1, const float* __restrict__ b1,
    const float* __restrict__ W2, const float* __restrict__ b2,
    const int* __restrict__ sele, float* __restrict__ xsum)
{
    __shared__ __align__(16) float wsh[128 * 128];  // staged weight panel (64 KB)
    __shared__ __align__(16) float sA[16][132];     // O rows, later gelu(h)
    __shared__ __align__(16) float xn[16][132];     // LN2 output
    __shared__ __align__(16) float cs[16][132];     // per-row masked contributions
    const int t = threadIdx.x;
    const int r0 = blockIdx.x * 16;
    {   // fold 4 key-slots + divide by E: thread = (row r, 8-col group)
        const int r = t >> 4, c8 = (t & 15) * 8;
        const int h = c8 >> 5;
        float es = 0.f;
        float v[8] = {0.f, 0.f, 0.f, 0.f, 0.f, 0.f, 0.f, 0.f};
        #pragma unroll
        for (int ks = 0; ks < KSPLIT; ++ks) {
            es += E[((size_t)ks * 4 + h) * 4096 + r0 + r];
            const float4 o1 = *(const float4*)&Oe[((size_t)ks * 4096 + r0 + r) * 128 + c8];
            const float4 o2 = *(const float4*)&Oe[((size_t)ks * 4096 + r0 + r) * 128 + c8 + 4];
            v[0] += o1.x; v[1] += o1.y; v[2] += o1.z; v[3] += o1.w;
            v[4] += o2.x; v[5] += o2.y; v[6] += o2.z; v[7] += o2.w;
        }
        const float rcp = 1.f / es;
        *(float4*)&sA[r][c8]     = make_float4(v[0] * rcp, v[1] * rcp, v[2] * rcp, v[3] * rcp);
        *(float4*)&sA[r][c8 + 4] = make_float4(v[4] * rcp, v[5] * rcp, v[6] * rcp, v[7] * rcp);
    }
    {   // stage outW -> wsh
        const float4* __restrict__ src = (const float4*)outW;
        float4* dst = (float4*)wsh;
        #pragma unroll
        for (int i = 0; i < 16; ++i) dst[t + i * 256] = src[t + i * 256];
    }
    __syncthreads();
    const int lane = t & 63;
    const int w = t >> 6;
    const int rp = w * 2 + (lane >> 5);
    const int c0 = (lane & 31) * 4;
    const int ra = rp * 2, rb = ra + 1;
    float x2a[4], x2b[4];
    {   // out projection + residual (weights from LDS)
        const float4 bb = *(const float4*)&outb[c0];
        float a0 = bb.x, a1 = bb.y, a2 = bb.z, a3 = bb.w;
        float b0 = bb.x, b1 = bb.y, b2 = bb.z, b3 = bb.w;
        #pragma unroll 8
        for (int k = 0; k < 128; ++k) {
            const float xva = sA[ra][k];
            const float xvb = sA[rb][k];
            const float4 wk = *(const float4*)&wsh[k * 128 + c0];
            a0 = fmaf(xva, wk.x, a0); a1 = fmaf(xva, wk.y, a1);
            a2 = fmaf(xva, wk.z, a2); a3 = fmaf(xva, wk.w, a3);
            b0 = fmaf(xvb, wk.x, b0); b1 = fmaf(xvb, wk.y, b1);
            b2 = fmaf(xvb, wk.z, b2); b3 = fmaf(xvb, wk.w, b3);
        }
        const float4 ea = *(const float4*)&eig[(size_t)(r0 + ra) * 128 + c0];
        const float4 eb = *(const float4*)&eig[(size_t)(r0 + rb) * 128 + c0];
        x2a[0] = ea.x + a0; x2a[1] = ea.y + a1; x2a[2] = ea.z + a2; x2a[3] = ea.w + a3;
        x2b[0] = eb.x + b0; x2b[1] = eb.y + b1; x2b[2] = eb.z + b2; x2b[3] = eb.w + b3;
    }
    {   // LN2 both rows — half-wave shuffle
        float sa = (x2a[0] + x2a[1]) + (x2a[2] + x2a[3]);
        float qa = (x2a[0] * x2a[0] + x2a[1] * x2a[1]) + (x2a[2] * x2a[2] + x2a[3] * x2a[3]);
        float sb = (x2b[0] + x2b[1]) + (x2b[2] + x2b[3]);
        float qb = (x2b[0] * x2b[0] + x2b[1] * x2b[1]) + (x2b[2] * x2b[2] + x2b[3] * x2b[3]);
        #pragma unroll
        for (int m = 1; m < 32; m <<= 1) {
            sa += __shfl_xor(sa, m, 32); qa += __shfl_xor(qa, m, 32);
            sb += __shfl_xor(sb, m, 32); qb += __shfl_xor(qb, m, 32);
        }
        const float ma = sa * (1.f / 128.f), mb = sb * (1.f / 128.f);
        const float ia = 1.f / sqrtf(qa * (1.f / 128.f) - ma * ma + 1e-5f);
        const float ib = 1.f / sqrtf(qb * (1.f / 128.f) - mb * mb + 1e-5f);
        const float4 gg = *(const float4*)&lg[c0];
        const float4 bb = *(const float4*)&lb[c0];
        *(float4*)&xn[ra][c0] = make_float4((x2a[0] - ma) * ia * gg.x + bb.x,
                                            (x2a[1] - ma) * ia * gg.y + bb.y,
                                            (x2a[2] - ma) * ia * gg.z + bb.z,
                                            (x2a[3] - ma) * ia * gg.w + bb.w);
        *(float4*)&xn[rb][c0] = make_float4((x2b[0] - mb) * ib * gg.x + bb.x,
                                            (x2b[1] - mb) * ib * gg.y + bb.y,
                                            (x2b[2] - mb) * ib * gg.z + bb.z,
                                            (x2b[3] - mb) * ib * gg.w + bb.w);
    }
    __syncthreads();
    {   // stage W1 -> wsh
        const float4* __restrict__ src = (const float4*)W1;
        float4* dst = (float4*)wsh;
        #pragma unroll
        for (int i = 0; i < 16; ++i) dst[t + i * 256] = src[t + i * 256];
    }
    __syncthreads();
    {   // FFN1 + exact gelu -> sA
        const float4 bb = *(const float4*)&b1[c0];
        float a0 = bb.x, a1 = bb.y, a2 = bb.z, a3 = bb.w;
        float b0 = bb.x, b1v = bb.y, b2v = bb.z, b3 = bb.w;
        #pragma unroll 8
        for (int k = 0; k < 128; ++k) {
            const float xva = xn[ra][k];
            const float xvb = xn[rb][k];
            const float4 wk = *(const float4*)&wsh[k * 128 + c0];
            a0 = fmaf(xva, wk.x, a0); a1 = fmaf(xva, wk.y, a1);
            a2 = fmaf(xva, wk.z, a2); a3 = fmaf(xva, wk.w, a3);
            b0 = fmaf(xvb, wk.x, b0); b1v = fmaf(xvb, wk.y, b1v);
            b2v = fmaf(xvb, wk.z, b2v); b3 = fmaf(xvb, wk.w, b3);
        }
        *(float4*)&sA[ra][c0] = make_float4(
            0.5f * a0 * (1.f + erff(a0 * 0.70710678118654752f)),
            0.5f * a1 * (1.f + erff(a1 * 0.70710678118654752f)),
            0.5f * a2 * (1.f + erff(a2 * 0.70710678118654752f)),
            0.5f * a3 * (1.f + erff(a3 * 0.70710678118654752f)));
        *(float4*)&sA[rb][c0] = make_float4(
            0.5f * b0 * (1.f + erff(b0 * 0.70710678118654752f)),
            0.5f * b1v * (1.f + erff(b1v * 0.70710678118654752f)),
            0.5f * b2v * (1.f + erff(b2v * 0.70710678118654752f)),
            0.5f * b3 * (1.f + erff(b3 * 0.70710678118654752f)));
    }
    __syncthreads();
    {   // stage W2 -> wsh
        const float4* __restrict__ src = (const float4*)W2;
        float4* dst = (float4*)wsh;
        #pragma unroll
        for (int i = 0; i < 16; ++i) dst[t + i * 256] = src[t + i * 256];
    }
    __syncthreads();
    {   // FFN2 + residual + masked per-row contributions
        const float4 bb = *(const float4*)&b2[c0];
        float a0 = bb.x, a1 = bb.y, a2 = bb.z, a3 = bb.w;
        float b0 = bb.x, b1v = bb.y, b2v = bb.z, b3 = bb.w;
        #pragma unroll 8
        for (int k = 0; k < 128; ++k) {
            const float xva = sA[ra][k];
            const float xvb = sA[rb][k];
            const float4 wk = *(const float4*)&wsh[k * 128 + c0];
            a0 = fmaf(xva, wk.x, a0); a1 = fmaf(xva, wk.y, a1);
            a2 = fmaf(xva, wk.z, a2); a3 = fmaf(xva, wk.w, a3);
            b0 = fmaf(xvb, wk.x, b0); b1v = fmaf(xvb, wk.y, b1v);
            b2v = fmaf(xvb, wk.z, b2v); b3 = fmaf(xvb, wk.w, b3);
        }
        const int nsel = sele[0];
        const bool ina = (r0 + ra) < nsel, inb2 = (r0 + rb) < nsel;
        *(float4*)&cs[ra][c0] = ina ? make_float4(x2a[0] + a0, x2a[1] + a1, x2a[2] + a2, x2a[3] + a3)
                                    : make_float4(0.f, 0.f, 0.f, 0.f);
        *(float4*)&cs[rb][c0] = inb2 ? make_float4(x2b[0] + b0, x2b[1] + b1v, x2b[2] + b2v, x2b[3] + b3)
                                     : make_float4(0.f, 0.f, 0.f, 0.f);
    }
    __syncthreads();
    if (t < 128) {
        float s = 0.f;
        #pragma unroll
        for (int rr = 0; rr < 16; ++rr) s += cs[rr][t];
        atomicAdd(&xsum[t], s);
    }
}

// ---------------- K5: pooled coefficients (parallel k-split) ----------------
__global__ __launch_bounds__(512) void k_coef(const float* __restrict__ xsum,
    const float* __restrict__ dscW, const float* __restrict__ dscb,
    const float* __restrict__ dwvW, const float* __restrict__ dwvb,
    const float* __restrict__ dssW, const float* __restrict__ dssb,
    const int* __restrict__ len, const int* __restrict__ sele,
    float* __restrict__ coef)
{
    __shared__ float xs[128];
    __shared__ float part[104][4];
    __shared__ float val[104];
    __shared__ float s2[2];
    const int t = threadIdx.x;
    if (t < 128) xs[t] = xsum[t];
    __syncthreads();
    const float invl = 1.f / ((float)len[0] + 1e-8f);
    const float ns = (float)sele[0];
    const int o = t >> 2, lk = t & 3;
    if (o < 104) {
        const float* Wp; int stride, col;
        if (o < 50)       { Wp = dscW; stride = 50; col = o; }
        else if (o < 100) { Wp = dwvW; stride = 50; col = o - 50; }
        else              { Wp = dssW; stride = 4;  col = o - 100; }
        float a = 0.f;
        #pragma unroll
        for (int kk = 0; kk < 32; ++kk) {
            const int k = lk * 32 + kk;
            a = fmaf(xs[k], Wp[k * stride + col], a);
        }
        part[o][lk] = a;
    }
    __syncthreads();
    if (t < 104) {
        const float bias = (t < 50) ? dscb[t] : ((t < 100) ? dwvb[t - 50] : dssb[t - 100]);
        float a = ((part[t][0] + part[t][1]) + (part[t][2] + part[t][3]) + ns * bias) * invl;
        val[t] = 1.f / (1.f + __expf(-a));
    }
    __syncthreads();
    if (t == 0) { float s = 0.f; for (int i = 0; i < 50; ++i) s += val[i]; s2[0] = s; }
    if (t == 1) { float s = 0.f; for (int i = 0; i < 50; ++i) s += val[50 + i]; s2[1] = s; }
    __syncthreads();
    if (t < 50) {
        coef[t]      = val[t] / (s2[0] + 1e-8f);
        coef[50 + t] = val[50 + t] / (s2[1] + 1e-8f);
    } else if (t >= 100 && t < 104) {
        coef[t] = val[t] * 5.0f;   // THRE
    }
}

// ---------------- K6: Chebyshev bases + combine + normalize ----------------
__global__ __launch_bounds__(128) void k_out(const float* __restrict__ eve,
    const float* __restrict__ coef, float* __restrict__ out)
{
    __shared__ float csc[50], cwv[50], cssh[4];
    const int t = threadIdx.x;
    if (t < 50) csc[t] = coef[t];
    else if (t < 100) cwv[t - 50] = coef[t];
    else if (t < 104) cssh[t - 100] = coef[t];
    __syncthreads();
    const int s = blockIdx.x * 128 + t;
    const float e = eve[s];
    float vals[5];
    {
        const float y = e - 1.f;
        float te = 1.f, to = y;
        float a = csc[0] * (0.5f * (1.f - to));
        const float y2 = 2.f * y;
        for (int i = 1; i < 50; ++i) {
            te = fmaf(y2, to, -te);
            to = fmaf(y2, te, -to);
            a = fmaf(csc[i], 0.5f * (1.f - to), a);
        }
        vals[0] = a;
    }
    #pragma unroll
    for (int j = 0; j < 4; ++j) {
        float f = e * cssh[j];
        if (f > 2.f) f = 0.f;
        const float y = f - 1.f;
        float te = 1.f, to = y;
        float a = cwv[0] * (0.5f * (1.f - te));
        const float y2 = 2.f * y;
        for (int i = 1; i < 50; ++i) {
            te = fmaf(y2, to, -te);
            to = fmaf(y2, te, -to);
            a = fmaf(cwv[i], 0.5f * (1.f - te), a);
        }
        vals[1 + j] = a;
    }
    float n2 = 0.f;
    #pragma unroll
    for (int k = 0; k < 5; ++k) n2 += vals[k] * vals[k];
    const float invn = 1.f / (sqrtf(n2) + 1e-8f);
    #pragma unroll
    for (int k = 0; k < 5; ++k) out[s * 5 + k] = vals[k] * invn;
}

extern "C" void kernel_launch(void* const* d_in, const int* in_sizes, int n_in,
                              void* d_out, int out_size, void* d_ws, size_t ws_size,
                              hipStream_t stream) {
    const float* eve  = (const float*)d_in[0];
    const int*   len  = (const int*)d_in[1];
    const int*   sele = (const int*)d_in[2];
    const float* eigW = (const float*)d_in[3];
    const float* eigB = (const float*)d_in[4];
    const float* mlg  = (const float*)d_in[5];
    const float* mlb  = (const float*)d_in[6];
    const float* inW  = (const float*)d_in[7];
    const float* inb  = (const float*)d_in[8];
    const float* outW = (const float*)d_in[9];
    const float* outb = (const float*)d_in[10];
    const float* flg  = (const float*)d_in[11];
    const float* flb  = (const float*)d_in[12];
    const float* W1   = (const float*)d_in[13];
    const float* b1   = (const float*)d_in[14];
    const float* W2   = (const float*)d_in[15];
    const float* b2   = (const float*)d_in[16];
    const float* dscW = (const float*)d_in[17];
    const float* dscb = (const float*)d_in[18];
    const float* dwvW = (const float*)d_in[19];
    const float* dwvb = (const float*)d_in[20];
    const float* dssW = (const float*)d_in[21];
    const float* dssb = (const float*)d_in[22];

    float* ws   = (float*)d_ws;
    float* eig  = ws;
    float* qkv  = ws + 524288;
    float* Oe   = ws + 2097152;
    float* E    = ws + 4194304;
    float* xsum = ws + 4259840;
    float* coef = ws + 4259968;
    unsigned short* Khi_g = (unsigned short*)(ws + 4260352);
    unsigned short* Klo_g = (unsigned short*)(ws + 4522496);
    unsigned short* Vt_g  = (unsigned short*)(ws + 4784640);
    float* out  = (float*)d_out;

    hipMemsetAsync(xsum, 0, 128 * sizeof(float), stream);
    k_embed<<<256, 256, 0, stream>>>(eve, eigW, eigB, mlg, mlb, inW, inb,
                                     eig, qkv, Khi_g, Klo_g, Vt_g);
    k_attn <<<dim3(64, 4, KSPLIT), 64, 0, stream>>>(qkv, Khi_g, Klo_g, Vt_g, sele, Oe, E);
    k_ffn  <<<256, 256, 0, stream>>>(eig, Oe, E, outW, outb, flg, flb, W1, b1, W2, b2, sele, xsum);
    k_coef <<<1, 512, 0, stream>>>(xsum, dscW, dscb, dwvW, dwvb, dssW, dssb, len, sele, coef);
    k_out  <<<32, 128, 0, stream>>>(eve, coef, out);
}

// Round 16
// 190.500 us; speedup vs baseline: 1.2315x; 1.2315x over previous
//
#include <hip/hip_runtime.h>
#include <math.h>

// Problem constants (B=1): S=4096, D=128, NHEADS=4, hd=32, N_COE=50, N_SCALES=4, THRE=5
//
// ws layout (floats):
//   eig   @ 0        (524288)
//   qkv   @ 524288   (1572864; only Q panel used, f32)
//   Oe    @ 2097152  (8*4096*128 = 4194304)
//   E     @ 6291456  (8*4*4096 = 131072)
//   xsum  @ 6422528  (128)
//   coef  @ 6422656  (128 pad)
//   Khi_g @ 6422784  [h][key][d] bf16 hi (262144 floats)
//   Klo_g @ 6684928  [h][key][d] bf16 lo
//   Vt_g  @ 6947072  [h*32+d][key] bf16
// total ~28.8 MB

#define SLOTS 8

typedef __attribute__((ext_vector_type(8))) short short8;   // 8 bf16
typedef __attribute__((ext_vector_type(4))) short short4v;  // 4 bf16 (8B)
typedef __attribute__((ext_vector_type(4))) float f32x4;

__device__ inline unsigned short f2bf(float x) {            // RNE f32->bf16 bits
    unsigned u = __float_as_uint(x);
    return (unsigned short)((u + 0x7FFFu + ((u >> 16) & 1u)) >> 16);
}
__device__ inline float bf2f(unsigned short h) { return __uint_as_float(((unsigned)h) << 16); }

// ---------------- K1: fused sine-encoding + eig GEMM + LN1 + qkv GEMM (round-14 proven) ----------------
__global__ __launch_bounds__(256) void k_embed(const float* __restrict__ eve,
    const float* __restrict__ eigW, const float* __restrict__ ebias,
    const float* __restrict__ g, const float* __restrict__ b,
    const float* __restrict__ inW, const float* __restrict__ inb,
    float* __restrict__ eig, float* __restrict__ qkv, unsigned short* __restrict__ Khi_g,
    unsigned short* __restrict__ Klo_g, unsigned short* __restrict__ Vt_g)
{
    __shared__ __align__(16) float wsh[129 * 128];   // staged weight panel (66 KB)
    __shared__ __align__(16) float se[16][132];      // [0..63]=sin, [64..127]=cos, [128]=e
    __shared__ __align__(16) float xn[16][132];      // LN1 output
    __shared__ __align__(16) unsigned short vsh[128][16];
    const int t = threadIdx.x;
    const int r0 = blockIdx.x * 16;
    {   // Phase A: sin/cos
        const int r = t >> 4, l4 = t & 15;
        const float e = eve[r0 + r];
        if (l4 == 0) se[r][128] = e;
        #pragma unroll
        for (int jj = 0; jj < 4; ++jj) {
            const int j = l4 * 4 + jj;
            const float div = __expf(-0.07195578415606394f * (float)(2 * j));
            const float pe = e * 100.0f * div;    // |pe| <= 200 rad
            se[r][j]      = __sinf(pe);
            se[r][64 + j] = __cosf(pe);
        }
    }
    {   // stage eigW (129 rows x 128) -> wsh
        const float4* __restrict__ src = (const float4*)eigW;
        float4* dst = (float4*)wsh;
        #pragma unroll
        for (int i = 0; i < 17; ++i) {
            const int f = t + i * 256;
            if (f < 4128) dst[f] = src[f];
        }
    }
    __syncthreads();
    const int lane = t & 63;
    const int w = t >> 6;
    const int rp = w * 2 + (lane >> 5);           // 0..7
    const int c0 = (lane & 31) * 4;
    const int ra = rp * 2, rb = ra + 1;
    float xa[4], xb[4];
    {   // Phase B: eig = eeig @ W + b (weights from LDS)
        const float4 w0 = *(const float4*)&wsh[c0];
        const float ea = se[ra][128], eb = se[rb][128];
        float a0 = ea * w0.x, a1 = ea * w0.y, a2 = ea * w0.z, a3 = ea * w0.w;
        float b0 = eb * w0.x, b1 = eb * w0.y, b2 = eb * w0.z, b3 = eb * w0.w;
        #pragma unroll 8
        for (int k = 0; k < 128; ++k) {
            const float xva = se[ra][k];
            const float xvb = se[rb][k];
            const float4 wk = *(const float4*)&wsh[(k + 1) * 128 + c0];
            a0 = fmaf(xva, wk.x, a0); a1 = fmaf(xva, wk.y, a1);
            a2 = fmaf(xva, wk.z, a2); a3 = fmaf(xva, wk.w, a3);
            b0 = fmaf(xvb, wk.x, b0); b1 = fmaf(xvb, wk.y, b1);
            b2 = fmaf(xvb, wk.z, b2); b3 = fmaf(xvb, wk.w, b3);
        }
        const float4 bb = *(const float4*)&ebias[c0];
        xa[0] = a0 + bb.x; xa[1] = a1 + bb.y; xa[2] = a2 + bb.z; xa[3] = a3 + bb.w;
        xb[0] = b0 + bb.x; xb[1] = b1 + bb.y; xb[2] = b2 + bb.z; xb[3] = b3 + bb.w;
        *(float4*)&eig[(size_t)(r0 + ra) * 128 + c0] = make_float4(xa[0], xa[1], xa[2], xa[3]);
        *(float4*)&eig[(size_t)(r0 + rb) * 128 + c0] = make_float4(xb[0], xb[1], xb[2], xb[3]);
    }
    {   // Phase C: LN1 — half-wave shuffle
        float sa = (xa[0] + xa[1]) + (xa[2] + xa[3]);
        float qa = (xa[0] * xa[0] + xa[1] * xa[1]) + (xa[2] * xa[2] + xa[3] * xa[3]);
        float sb = (xb[0] + xb[1]) + (xb[2] + xb[3]);
        float qb = (xb[0] * xb[0] + xb[1] * xb[1]) + (xb[2] * xb[2] + xb[3] * xb[3]);
        #pragma unroll
        for (int m = 1; m < 32; m <<= 1) {
            sa += __shfl_xor(sa, m, 32); qa += __shfl_xor(qa, m, 32);
            sb += __shfl_xor(sb, m, 32); qb += __shfl_xor(qb, m, 32);
        }
        const float ma = sa * (1.f / 128.f), mb = sb * (1.f / 128.f);
        const float ia = 1.f / sqrtf(qa * (1.f / 128.f) - ma * ma + 1e-5f);
        const float ib = 1.f / sqrtf(qb * (1.f / 128.f) - mb * mb + 1e-5f);
        const float4 gg = *(const float4*)&g[c0];
        const float4 bb = *(const float4*)&b[c0];
        *(float4*)&xn[ra][c0] = make_float4((xa[0] - ma) * ia * gg.x + bb.x,
                                            (xa[1] - ma) * ia * gg.y + bb.y,
                                            (xa[2] - ma) * ia * gg.z + bb.z,
                                            (xa[3] - ma) * ia * gg.w + bb.w);
        *(float4*)&xn[rb][c0] = make_float4((xb[0] - mb) * ib * gg.x + bb.x,
                                            (xb[1] - mb) * ib * gg.y + bb.y,
                                            (xb[2] - mb) * ib * gg.z + bb.z,
                                            (xb[3] - mb) * ib * gg.w + bb.w);
    }
    // Phase D: qkv GEMM, one panel at a time
    const int rowa = r0 + ra, rowb = r0 + rb;
    for (int p = 0; p < 3; ++p) {
        __syncthreads();
        {   // stage inW panel p
            const float4* __restrict__ src = (const float4*)inW;   // row = 96 float4
            float4* dst = (float4*)wsh;
            #pragma unroll
            for (int i = 0; i < 16; ++i) {
                const int f = t + i * 256;
                const int k = f >> 5, c4 = f & 31;
                dst[f] = src[k * 96 + p * 32 + c4];
            }
        }
        __syncthreads();
        float A[4], B[4];
        {
            const float4 bb = *(const float4*)&inb[p * 128 + c0];
            A[0] = bb.x; A[1] = bb.y; A[2] = bb.z; A[3] = bb.w;
            B[0] = bb.x; B[1] = bb.y; B[2] = bb.z; B[3] = bb.w;
        }
        #pragma unroll 8
        for (int k = 0; k < 128; ++k) {
            const float xva = xn[ra][k];
            const float xvb = xn[rb][k];
            const float4 wk = *(const float4*)&wsh[k * 128 + c0];
            A[0] = fmaf(xva, wk.x, A[0]); A[1] = fmaf(xva, wk.y, A[1]);
            A[2] = fmaf(xva, wk.z, A[2]); A[3] = fmaf(xva, wk.w, A[3]);
            B[0] = fmaf(xvb, wk.x, B[0]); B[1] = fmaf(xvb, wk.y, B[1]);
            B[2] = fmaf(xvb, wk.z, B[2]); B[3] = fmaf(xvb, wk.w, B[3]);
        }
        if (p == 0) {
            *(float4*)&qkv[(size_t)rowa * 384 + c0] = make_float4(A[0], A[1], A[2], A[3]);
            *(float4*)&qkv[(size_t)rowb * 384 + c0] = make_float4(B[0], B[1], B[2], B[3]);
        } else if (p == 1) {
            const int h = c0 >> 5, d = c0 & 31;
            unsigned short h4[4], l4v[4];
            #pragma unroll
            for (int i = 0; i < 4; ++i) { h4[i] = f2bf(A[i]); l4v[i] = f2bf(A[i] - bf2f(h4[i])); }
            *(uint2*)&Khi_g[((size_t)h * 4096 + rowa) * 32 + d] = *(uint2*)h4;
            *(uint2*)&Klo_g[((size_t)h * 4096 + rowa) * 32 + d] = *(uint2*)l4v;
            #pragma unroll
            for (int i = 0; i < 4; ++i) { h4[i] = f2bf(B[i]); l4v[i] = f2bf(B[i] - bf2f(h4[i])); }
            *(uint2*)&Khi_g[((size_t)h * 4096 + rowb) * 32 + d] = *(uint2*)h4;
            *(uint2*)&Klo_g[((size_t)h * 4096 + rowb) * 32 + d] = *(uint2*)l4v;
        } else {
            #pragma unroll
            for (int i = 0; i < 4; ++i) {
                vsh[c0 + i][ra] = f2bf(A[i]);
                vsh[c0 + i][rb] = f2bf(B[i]);
            }
        }
    }
    __syncthreads();
    if (t < 128) {
        const uint4 v0 = *(const uint4*)&vsh[t][0];
        const uint4 v1 = *(const uint4*)&vsh[t][8];
        *(uint4*)&Vt_g[(size_t)t * 4096 + r0]     = v0;
        *(uint4*)&Vt_g[(size_t)t * 4096 + r0 + 8] = v1;
    }
}

// ---------------- K3: MFMA flash attention — NO staging, NO barriers ----------------
// Block = 256 threads / 4 waves. Each wave: 64 queries (4 Q-frags) x its own 512-key range
// (slot = blockIdx.z*4 + wv). K/V fragments loaded DIRECTLY from L2-resident global in
// MFMA lane layout (16 complete 64B lines per fragment). P round-trips via wave-private
// LDS (same-wave DS ordering -> zero __syncthreads). Chunk loop is a pure global-load ->
// MFMA stream the compiler can pipeline freely.
#define PSTR 72

__global__ __launch_bounds__(256) void k_attn(const float* __restrict__ qkv,
    const unsigned short* __restrict__ Khi_g, const unsigned short* __restrict__ Klo_g,
    const unsigned short* __restrict__ Vt_g,
    const int* __restrict__ sele, float* __restrict__ Oe, float* __restrict__ E)
{
    __shared__ __align__(16) unsigned short Pb[4][64 * PSTR];   // wave-private P (36.9 KB)

    const int t = threadIdx.x;
    const int lane = t & 63;
    const int l = lane & 15;
    const int quad = lane >> 4;
    const int wv = __builtin_amdgcn_readfirstlane(t >> 6);
    const int qb = blockIdx.x;                  // 64 q-blocks of 64 queries
    const int h  = blockIdx.y;                  // 4 heads
    const int slot = blockIdx.z * 4 + wv;       // 8 key slots of 512
    const int nk = sele[0];
    unsigned short* __restrict__ Pw = Pb[wv];

    short8 qhi[4], qlo[4];                      // queries qb*64 + qf*16 + l
    #pragma unroll
    for (int qf = 0; qf < 4; ++qf) {
        const float* __restrict__ qr =
            qkv + (size_t)(qb * 64 + qf * 16 + l) * 384 + h * 32 + quad * 8;
        const float4 a = *(const float4*)qr;
        const float4 b = *(const float4*)(qr + 4);
        const float sc = 0.17677669529663687f;  // 1/sqrt(32)
        float v[8] = {a.x * sc, a.y * sc, a.z * sc, a.w * sc, b.x * sc, b.y * sc, b.z * sc, b.w * sc};
        #pragma unroll
        for (int j = 0; j < 8; ++j) {
            const unsigned short hb = f2bf(v[j]);
            qhi[qf][j] = (short)hb;
            qlo[qf][j] = (short)f2bf(v[j] - bf2f(hb));
        }
    }
    f32x4 accO[4][2];
    #pragma unroll
    for (int qf = 0; qf < 4; ++qf) {
        accO[qf][0] = (f32x4){0.f, 0.f, 0.f, 0.f};
        accO[qf][1] = (f32x4){0.f, 0.f, 0.f, 0.f};
    }
    float elane[4] = {0.f, 0.f, 0.f, 0.f};

    for (int ch = 0; ch < 8; ++ch) {
        const int keybase = slot * 512 + ch * 64;
        // QK^T transposed (A=K-frag from global, B=Q-frag in regs) -> P to wave-private LDS
        #pragma unroll
        for (int tile = 0; tile < 4; ++tile) {
            const size_t krow = (size_t)h * 4096 + keybase + tile * 16 + l;
            const short8 kh = *(const short8*)&Khi_g[krow * 32 + quad * 8];
            const short8 kw = *(const short8*)&Klo_g[krow * 32 + quad * 8];
            const int kg0 = keybase + tile * 16 + quad * 4;
            #pragma unroll
            for (int qf = 0; qf < 4; ++qf) {
                f32x4 S = {0.f, 0.f, 0.f, 0.f};
                S = __builtin_amdgcn_mfma_f32_16x16x32_bf16(kh, qhi[qf], S, 0, 0, 0);
                S = __builtin_amdgcn_mfma_f32_16x16x32_bf16(kw, qhi[qf], S, 0, 0, 0);
                S = __builtin_amdgcn_mfma_f32_16x16x32_bf16(kh, qlo[qf], S, 0, 0, 0);
                short4v pw;
                #pragma unroll
                for (int r = 0; r < 4; ++r) {
                    const float p = (kg0 + r < nk) ? __expf(S[r]) : 0.f;
                    elane[qf] += p;
                    pw[r] = (short)f2bf(p);
                }
                *(short4v*)&Pw[(qf * 16 + l) * PSTR + tile * 16 + quad * 4] = pw;
            }
        }
        // PV: K=32 over 2 tile-pairs; V fragments direct from global, shared across qf
        #pragma unroll
        for (int pair = 0; pair < 2; ++pair) {
            short8 pa[4];
            #pragma unroll
            for (int qf = 0; qf < 4; ++qf)
                pa[qf] = *(const short8*)&Pw[(qf * 16 + l) * PSTR + pair * 32 + quad * 8];
            #pragma unroll
            for (int dt = 0; dt < 2; ++dt) {
                const short8 vb = *(const short8*)
                    &Vt_g[((size_t)h * 32 + dt * 16 + l) * 4096 + keybase + pair * 32 + quad * 8];
                #pragma unroll
                for (int qf = 0; qf < 4; ++qf)
                    accO[qf][dt] = __builtin_amdgcn_mfma_f32_16x16x32_bf16(pa[qf], vb, accO[qf][dt], 0, 0, 0);
            }
        }
    }
    #pragma unroll
    for (int qf = 0; qf < 4; ++qf) {
        float e = elane[qf];
        e += __shfl_xor(e, 16, 64);
        e += __shfl_xor(e, 32, 64);
        if (lane < 16)
            E[((size_t)slot * 4 + h) * 4096 + qb * 64 + qf * 16 + l] = e;
        #pragma unroll
        for (int r = 0; r < 4; ++r) {
            const size_t row = qb * 64 + qf * 16 + quad * 4 + r;
            Oe[((size_t)slot * 4096 + row) * 128 + h * 32 + l]      = accO[qf][0][r];
            Oe[((size_t)slot * 4096 + row) * 128 + h * 32 + 16 + l] = accO[qf][1][r];
        }
    }
}

// ---------------- K4: fold 8 slots + out-proj + residual + LN2 + FFN + column-sum ----------------
__global__ __launch_bounds__(256) void k_ffn(const float* __restrict__ eig,
    const float* __restrict__ Oe, const float* __restrict__ E,
    const float* __restrict__ outW, const float* __restrict__ outb,
    const float* __restrict__ lg, const float* __restrict__ lb,
    const float* __restrict__ W1, const float* __restrict__ b1,
    const float* __restrict__ W2, const float* __restrict__ b2,
    const int* __restrict__ sele, float* __restrict__ xsum)
{
    __shared__ __align__(16) float wsh[128 * 128];  // staged weight panel (64 KB)
    __shared__ __align__(16) float sA[16][132];     // O rows, later gelu(h)
    __shared__ __align__(16) float xn[16][132];     // LN2 output
    __shared__ __align__(16) float cs[16][132];     // per-row masked contributions
    const int t = threadIdx.x;
    const int r0 = blockIdx.x * 16;
    {   // fold 8 key-slots + divide by E
        const int r = t >> 4, c8 = (t & 15) * 8;
        const int h = c8 >> 5;
        float es = 0.f;
        float v[8] = {0.f, 0.f, 0.f, 0.f, 0.f, 0.f, 0.f, 0.f};
        #pragma unroll
        for (int ks = 0; ks < SLOTS; ++ks) {
            es += E[((size_t)ks * 4 + h) * 4096 + r0 + r];
            const float4 o1 = *(const float4*)&Oe[((size_t)ks * 4096 + r0 + r) * 128 + c8];
            const float4 o2 = *(const float4*)&Oe[((size_t)ks * 4096 + r0 + r) * 128 + c8 + 4];
            v[0] += o1.x; v[1] += o1.y; v[2] += o1.z; v[3] += o1.w;
            v[4] += o2.x; v[5] += o2.y; v[6] += o2.z; v[7] += o2.w;
        }
        const float rcp = 1.f / es;
        *(float4*)&sA[r][c8]     = make_float4(v[0] * rcp, v[1] * rcp, v[2] * rcp, v[3] * rcp);
        *(float4*)&sA[r][c8 + 4] = make_float4(v[4] * rcp, v[5] * rcp, v[6] * rcp, v[7] * rcp);
    }
    {   // stage outW -> wsh
        const float4* __restrict__ src = (const float4*)outW;
        float4* dst = (float4*)wsh;
        #pragma unroll
        for (int i = 0; i < 16; ++i) dst[t + i * 256] = src[t + i * 256];
    }
    __syncthreads();
    const int lane = t & 63;
    const int w = t >> 6;
    const int rp = w * 2 + (lane >> 5);
    const int c0 = (lane & 31) * 4;
    const int ra = rp * 2, rb = ra + 1;
    float x2a[4], x2b[4];
    {   // out projection + residual (weights from LDS)
        const float4 bb = *(const float4*)&outb[c0];
        float a0 = bb.x, a1 = bb.y, a2 = bb.z, a3 = bb.w;
        float b0 = bb.x, b1 = bb.y, b2 = bb.z, b3 = bb.w;
        #pragma unroll 8
        for (int k = 0; k < 128; ++k) {
            const float xva = sA[ra][k];
            const float xvb = sA[rb][k];
            const float4 wk = *(const float4*)&wsh[k * 128 + c0];
            a0 = fmaf(xva, wk.x, a0); a1 = fmaf(xva, wk.y, a1);
            a2 = fmaf(xva, wk.z, a2); a3 = fmaf(xva, wk.w, a3);
            b0 = fmaf(xvb, wk.x, b0); b1 = fmaf(xvb, wk.y, b1);
            b2 = fmaf(xvb, wk.z, b2); b3 = fmaf(xvb, wk.w, b3);
        }
        const float4 ea = *(const float4*)&eig[(size_t)(r0 + ra) * 128 + c0];
        const float4 eb = *(const float4*)&eig[(size_t)(r0 + rb) * 128 + c0];
        x2a[0] = ea.x + a0; x2a[1] = ea.y + a1; x2a[2] = ea.z + a2; x2a[3] = ea.w + a3;
        x2b[0] = eb.x + b0; x2b[1] = eb.y + b1; x2b[2] = eb.z + b2; x2b[3] = eb.w + b3;
    }
    {   // LN2 both rows — half-wave shuffle
        float sa = (x2a[0] + x2a[1]) + (x2a[2] + x2a[3]);
        float qa = (x2a[0] * x2a[0] + x2a[1] * x2a[1]) + (x2a[2] * x2a[2] + x2a[3] * x2a[3]);
        float sb = (x2b[0] + x2b[1]) + (x2b[2] + x2b[3]);
        float qb = (x2b[0] * x2b[0] + x2b[1] * x2b[1]) + (x2b[2] * x2b[2] + x2b[3] * x2b[3]);
        #pragma unroll
        for (int m = 1; m < 32; m <<= 1) {
            sa += __shfl_xor(sa, m, 32); qa += __shfl_xor(qa, m, 32);
            sb += __shfl_xor(sb, m, 32); qb += __shfl_xor(qb, m, 32);
        }
        const float ma = sa * (1.f / 128.f), mb = sb * (1.f / 128.f);
        const float ia = 1.f / sqrtf(qa * (1.f / 128.f) - ma * ma + 1e-5f);
        const float ib = 1.f / sqrtf(qb * (1.f / 128.f) - mb * mb + 1e-5f);
        const float4 gg = *(const float4*)&lg[c0];
        const float4 bb = *(const float4*)&lb[c0];
        *(float4*)&xn[ra][c0] = make_float4((x2a[0] - ma) * ia * gg.x + bb.x,
                                            (x2a[1] - ma) * ia * gg.y + bb.y,
                                            (x2a[2] - ma) * ia * gg.z + bb.z,
                                            (x2a[3] - ma) * ia * gg.w + bb.w);
        *(float4*)&xn[rb][c0] = make_float4((x2b[0] - mb) * ib * gg.x + bb.x,
                                            (x2b[1] - mb) * ib * gg.y + bb.y,
                                            (x2b[2] - mb) * ib * gg.z + bb.z,
                                            (x2b[3] - mb) * ib * gg.w + bb.w);
    }
    __syncthreads();
    {   // stage W1 -> wsh
        const float4* __restrict__ src = (const float4*)W1;
        float4* dst = (float4*)wsh;
        #pragma unroll
        for (int i = 0; i < 16; ++i) dst[t + i * 256] = src[t + i * 256];
    }
    __syncthreads();
    {   // FFN1 + exact gelu -> sA
        const float4 bb = *(const float4*)&b1[c0];
        float a0 = bb.x, a1 = bb.y, a2 = bb.z, a3 = bb.w;
        float b0 = bb.x, b1v = bb.y, b2v = bb.z, b3 = bb.w;
        #pragma unroll 8
        for (int k = 0; k < 128; ++k) {
            const float xva = xn[ra][k];
            const float xvb = xn[rb][k];
            const float4 wk = *(const float4*)&wsh[k * 128 + c0];
            a0 = fmaf(xva, wk.x, a0); a1 = fmaf(xva, wk.y, a1);
            a2 = fmaf(xva, wk.z, a2); a3 = fmaf(xva, wk.w, a3);
            b0 = fmaf(xvb, wk.x, b0); b1v = fmaf(xvb, wk.y, b1v);
            b2v = fmaf(xvb, wk.z, b2v); b3 = fmaf(xvb, wk.w, b3);
        }
        *(float4*)&sA[ra][c0] = make_float4(
            0.5f * a0 * (1.f + erff(a0 * 0.70710678118654752f)),
            0.5f * a1 * (1.f + erff(a1 * 0.70710678118654752f)),
            0.5f * a2 * (1.f + erff(a2 * 0.70710678118654752f)),
            0.5f * a3 * (1.f + erff(a3 * 0.70710678118654752f)));
        *(float4*)&sA[rb][c0] = make_float4(
            0.5f * b0 * (1.f + erff(b0 * 0.70710678118654752f)),
            0.5f * b1v * (1.f + erff(b1v * 0.70710678118654752f)),
            0.5f * b2v * (1.f + erff(b2v * 0.70710678118654752f)),
            0.5f * b3 * (1.f + erff(b3 * 0.70710678118654752f)));
    }
    __syncthreads();
    {   // stage W2 -> wsh
        const float4* __restrict__ src = (const float4*)W2;
        float4* dst = (float4*)wsh;
        #pragma unroll
        for (int i = 0; i < 16; ++i) dst[t + i * 256] = src[t + i * 256];
    }
    __syncthreads();
    {   // FFN2 + residual + masked per-row contributions
        const float4 bb = *(const float4*)&b2[c0];
        float a0 = bb.x, a1 = bb.y, a2 = bb.z, a3 = bb.w;
        float b0 = bb.x, b1v = bb.y, b2v = bb.z, b3 = bb.w;
        #pragma unroll 8
        for (int k = 0; k < 128; ++k) {
            const float xva = sA[ra][k];
            const float xvb = sA[rb][k];
            const float4 wk = *(const float4*)&wsh[k * 128 + c0];
            a0 = fmaf(xva, wk.x, a0); a1 = fmaf(xva, wk.y, a1);
            a2 = fmaf(xva, wk.z, a2); a3 = fmaf(xva, wk.w, a3);
            b0 = fmaf(xvb, wk.x, b0); b1v = fmaf(xvb, wk.y, b1v);
            b2v = fmaf(xvb, wk.z, b2v); b3 = fmaf(xvb, wk.w, b3);
        }
        const int nsel = sele[0];
        const bool ina = (r0 + ra) < nsel, inb2 = (r0 + rb) < nsel;
        *(float4*)&cs[ra][c0] = ina ? make_float4(x2a[0] + a0, x2a[1] + a1, x2a[2] + a2, x2a[3] + a3)
                                    : make_float4(0.f, 0.f, 0.f, 0.f);
        *(float4*)&cs[rb][c0] = inb2 ? make_float4(x2b[0] + b0, x2b[1] + b1v, x2b[2] + b2v, x2b[3] + b3)
                                     : make_float4(0.f, 0.f, 0.f, 0.f);
    }
    __syncthreads();
    if (t < 128) {
        float s = 0.f;
        #pragma unroll
        for (int rr = 0; rr < 16; ++rr) s += cs[rr][t];
        atomicAdd(&xsum[t], s);
    }
}

// ---------------- K5: pooled coefficients (parallel k-split) ----------------
__global__ __launch_bounds__(512) void k_coef(const float* __restrict__ xsum,
    const float* __restrict__ dscW, const float* __restrict__ dscb,
    const float* __restrict__ dwvW, const float* __restrict__ dwvb,
    const float* __restrict__ dssW, const float* __restrict__ dssb,
    const int* __restrict__ len, const int* __restrict__ sele,
    float* __restrict__ coef)
{
    __shared__ float xs[128];
    __shared__ float part[104][4];
    __shared__ float val[104];
    __shared__ float s2[2];
    const int t = threadIdx.x;
    if (t < 128) xs[t] = xsum[t];
    __syncthreads();
    const float invl = 1.f / ((float)len[0] + 1e-8f);
    const float ns = (float)sele[0];
    const int o = t >> 2, lk = t & 3;
    if (o < 104) {
        const float* Wp; int stride, col;
        if (o < 50)       { Wp = dscW; stride = 50; col = o; }
        else if (o < 100) { Wp = dwvW; stride = 50; col = o - 50; }
        else              { Wp = dssW; stride = 4;  col = o - 100; }
        float a = 0.f;
        #pragma unroll
        for (int kk = 0; kk < 32; ++kk) {
            const int k = lk * 32 + kk;
            a = fmaf(xs[k], Wp[k * stride + col], a);
        }
        part[o][lk] = a;
    }
    __syncthreads();
    if (t < 104) {
        const float bias = (t < 50) ? dscb[t] : ((t < 100) ? dwvb[t - 50] : dssb[t - 100]);
        float a = ((part[t][0] + part[t][1]) + (part[t][2] + part[t][3]) + ns * bias) * invl;
        val[t] = 1.f / (1.f + __expf(-a));
    }
    __syncthreads();
    if (t == 0) { float s = 0.f; for (int i = 0; i < 50; ++i) s += val[i]; s2[0] = s; }
    if (t == 1) { float s = 0.f; for (int i = 0; i < 50; ++i) s += val[50 + i]; s2[1] = s; }
    __syncthreads();
    if (t < 50) {
        coef[t]      = val[t] / (s2[0] + 1e-8f);
        coef[50 + t] = val[50 + t] / (s2[1] + 1e-8f);
    } else if (t >= 100 && t < 104) {
        coef[t] = val[t] * 5.0f;   // THRE
    }
}

// ---------------- K6: Chebyshev bases + combine + normalize ----------------
__global__ __launch_bounds__(128) void k_out(const float* __restrict__ eve,
    const float* __restrict__ coef, float* __restrict__ out)
{
    __shared__ float csc[50], cwv[50], cssh[4];
    const int t = threadIdx.x;
    if (t < 50) csc[t] = coef[t];
    else if (t < 100) cwv[t - 50] = coef[t];
    else if (t < 104) cssh[t - 100] = coef[t];
    __syncthreads();
    const int s = blockIdx.x * 128 + t;
    const float e = eve[s];
    float vals[5];
    {
        const float y = e - 1.f;
        float te = 1.f, to = y;
        float a = csc[0] * (0.5f * (1.f - to));
        const float y2 = 2.f * y;
        for (int i = 1; i < 50; ++i) {
            te = fmaf(y2, to, -te);
            to = fmaf(y2, te, -to);
            a = fmaf(csc[i], 0.5f * (1.f - to), a);
        }
        vals[0] = a;
    }
    #pragma unroll
    for (int j = 0; j < 4; ++j) {
        float f = e * cssh[j];
        if (f > 2.f) f = 0.f;
        const float y = f - 1.f;
        float te = 1.f, to = y;
        float a = cwv[0] * (0.5f * (1.f - te));
        const float y2 = 2.f * y;
        for (int i = 1; i < 50; ++i) {
            te = fmaf(y2, to, -te);
            to = fmaf(y2, te, -to);
            a = fmaf(cwv[i], 0.5f * (1.f - te), a);
        }
        vals[1 + j] = a;
    }
    float n2 = 0.f;
    #pragma unroll
    for (int k = 0; k < 5; ++k) n2 += vals[k] * vals[k];
    const float invn = 1.f / (sqrtf(n2) + 1e-8f);
    #pragma unroll
    for (int k = 0; k < 5; ++k) out[s * 5 + k] = vals[k] * invn;
}

extern "C" void kernel_launch(void* const* d_in, const int* in_sizes, int n_in,
                              void* d_out, int out_size, void* d_ws, size_t ws_size,
                              hipStream_t stream) {
    const float* eve  = (const float*)d_in[0];
    const int*   len  = (const int*)d_in[1];
    const int*   sele = (const int*)d_in[2];
    const float* eigW = (const float*)d_in[3];
    const float* eigB = (const float*)d_in[4];
    const float* mlg  = (const float*)d_in[5];
    const float* mlb  = (const float*)d_in[6];
    const float* inW  = (const float*)d_in[7];
    const float* inb  = (const float*)d_in[8];
    const float* outW = (const float*)d_in[9];
    const float* outb = (const float*)d_in[10];
    const float* flg  = (const float*)d_in[11];
    const float* flb  = (const float*)d_in[12];
    const float* W1   = (const float*)d_in[13];
    const float* b1   = (const float*)d_in[14];
    const float* W2   = (const float*)d_in[15];
    const float* b2   = (const float*)d_in[16];
    const float* dscW = (const float*)d_in[17];
    const float* dscb = (const float*)d_in[18];
    const float* dwvW = (const float*)d_in[19];
    const float* dwvb = (const float*)d_in[20];
    const float* dssW = (const float*)d_in[21];
    const float* dssb = (const float*)d_in[22];

    float* ws   = (float*)d_ws;
    float* eig  = ws;
    float* qkv  = ws + 524288;
    float* Oe   = ws + 2097152;
    float* E    = ws + 6291456;
    float* xsum = ws + 6422528;
    float* coef = ws + 6422656;
    unsigned short* Khi_g = (unsigned short*)(ws + 6422784);
    unsigned short* Klo_g = (unsigned short*)(ws + 6684928);
    unsigned short* Vt_g  = (unsigned short*)(ws + 6947072);
    float* out  = (float*)d_out;

    hipMemsetAsync(xsum, 0, 128 * sizeof(float), stream);
    k_embed<<<256, 256, 0, stream>>>(eve, eigW, eigB, mlg, mlb, inW, inb,
                                     eig, qkv, Khi_g, Klo_g, Vt_g);
    k_attn <<<dim3(64, 4, 2), 256, 0, stream>>>(qkv, Khi_g, Klo_g, Vt_g, sele, Oe, E);
    k_ffn  <<<256, 256, 0, stream>>>(eig, Oe, E, outW, outb, flg, flb, W1, b1, W2, b2, sele, xsum);
    k_coef <<<1, 512, 0, stream>>>(xsum, dscW, dscb, dwvW, dwvb, dssW, dssb, len, sele, coef);
    k_out  <<<32, 128, 0, stream>>>(eve, coef, out);
}